// Round 5
// baseline (426.229 us; speedup 1.0000x reference)
//
#include <hip/hip_runtime.h>

typedef short short8 __attribute__((ext_vector_type(8)));
typedef float f32x4 __attribute__((ext_vector_type(4)));
typedef unsigned short u16;

#define MFMA16(a, b, c) __builtin_amdgcn_mfma_f32_16x16x32_bf16(a, b, c, 0, 0, 0)
#define GLD_LDS(g, l)                                                          \
  __builtin_amdgcn_global_load_lds(                                            \
      (__attribute__((address_space(1))) void*)(void*)(g),                     \
      (__attribute__((address_space(3))) void*)(l), 16, 0, 0)

__device__ __forceinline__ u16 f2bf(float f) {
  union { float f; unsigned u; } x; x.f = f;
  unsigned r = x.u + 0x7fffu + ((x.u >> 16) & 1u);
  return (u16)(r >> 16);
}

__device__ __forceinline__ short8 pack8(float4 a, float4 b) {
  short8 r;
  r[0] = (short)f2bf(a.x); r[1] = (short)f2bf(a.y);
  r[2] = (short)f2bf(a.z); r[3] = (short)f2bf(a.w);
  r[4] = (short)f2bf(b.x); r[5] = (short)f2bf(b.y);
  r[6] = (short)f2bf(b.z); r[7] = (short)f2bf(b.w);
  return r;
}

// ---------------- kernel 0: prep ----------------
// blocks 0..255: WoT2[n][h2*64+i] = bf16( sum_j Wv[i][j] * Wo[h2*64+j][n] )
// block 256:     Mt[n][k]         = bf16( sum_d Wk[n][d] * Wq[k][d] )
__global__ __launch_bounds__(256) void prep(const float* __restrict__ Wv,
                                            const float* __restrict__ Wk,
                                            const float* __restrict__ Wq,
                                            const float* __restrict__ Wo,
                                            u16* __restrict__ WoT2,
                                            u16* __restrict__ Mt) {
  __shared__ __align__(16) float A[64][65];
  __shared__ __align__(16) float B[64][68];
  const int t = threadIdx.x;
  const int r = t >> 2, c = (t & 3) * 16;
  if (blockIdx.x < 256) {
    const int tr = blockIdx.x >> 4, tc = blockIdx.x & 15;
#pragma unroll
    for (int u = 0; u < 4; ++u)
      *(float4*)&A[r][c + u * 4] = *(const float4*)(Wv + r * 64 + c + u * 4);
#pragma unroll
    for (int u = 0; u < 4; ++u)
      *(float4*)&B[r][c + u * 4] =
          *(const float4*)(Wo + (tr * 64 + r) * 1024 + tc * 64 + c + u * 4);
    __syncthreads();
    const int n = t & 63, i0 = (t >> 6) * 16;
    float acc[16];
#pragma unroll
    for (int ii = 0; ii < 16; ++ii) acc[ii] = 0.f;
    for (int j = 0; j < 64; ++j) {
      const float wo = B[j][n];
#pragma unroll
      for (int ii = 0; ii < 16; ++ii) acc[ii] += A[i0 + ii][j] * wo;
    }
    u16* dst = WoT2 + (size_t)(tc * 64 + n) * 1024 + tr * 64 + i0;
    short8 o0, o1;
#pragma unroll
    for (int jj = 0; jj < 8; ++jj) { o0[jj] = (short)f2bf(acc[jj]); o1[jj] = (short)f2bf(acc[8 + jj]); }
    *(short8*)(void*)dst = o0;
    *(short8*)(void*)(dst + 8) = o1;
  } else {
#pragma unroll
    for (int u = 0; u < 4; ++u)
      *(float4*)&A[r][c + u * 4] = *(const float4*)(Wq + r * 64 + c + u * 4);
#pragma unroll
    for (int u = 0; u < 4; ++u)
      *(float4*)&B[r][c + u * 4] = *(const float4*)(Wk + r * 64 + c + u * 4);
    __syncthreads();
    const int n = t & 63, k0 = (t >> 6) * 16;
    float acc[16];
#pragma unroll
    for (int ii = 0; ii < 16; ++ii) acc[ii] = 0.f;
    for (int d = 0; d < 64; ++d) {
      const float wk = B[n][d];
#pragma unroll
      for (int kk = 0; kk < 16; ++kk) acc[kk] += A[k0 + kk][d] * wk;
    }
    u16* dst = Mt + n * 64 + k0;
    short8 o0, o1;
#pragma unroll
    for (int jj = 0; jj < 8; ++jj) { o0[jj] = (short)f2bf(acc[jj]); o1[jj] = (short)f2bf(acc[8 + jj]); }
    *(short8*)(void*)dst = o0;
    *(short8*)(void*)(dst + 8) = o1;
  }
}

// ---------------- kernel 1: fused attention (per position) ----------------
// energy = (xq @ M) @ xk^T ; softmax ; o = P @ xv ; out2 natural [n][l][h][d]
// grid 4096 x 256: wave handles 2 positions; 6 blocks/CU resident.
// LDS shapes: t is 16x64 (needs full 64+pad cols!), vT 64x16, p 16x16.
__global__ __launch_bounds__(256, 6) void attn_kernel(
    const float* __restrict__ values, const float* __restrict__ keys,
    const float* __restrict__ query, const int* __restrict__ mask,
    const u16* __restrict__ Mt, float* __restrict__ attn,
    u16* __restrict__ out2) {
  __shared__ __align__(16) u16 t_lds[4][16][72];   // t (16x64), then o
  __shared__ __align__(16) u16 vT_lds[4][64][24];  // [wave][d][g]
  __shared__ __align__(16) u16 p_lds[4][16][24];   // [wave][h][g]

  const int tid = threadIdx.x;
  const int w = tid >> 6, lane = tid & 63;
  const int g16 = lane & 15;
  const int q4 = lane >> 4;
  const int kbase = q4 * 8;
  const int mrow = q4 * 4;

  // M^T fragments (B-operand of t = xq @ M), resident.
  short8 mtf[2][4];
#pragma unroll
  for (int kb = 0; kb < 2; ++kb)
#pragma unroll
    for (int nc = 0; nc < 4; ++nc)
      mtf[kb][nc] =
          *(const short8*)(Mt + (nc * 16 + g16) * 64 + kb * 32 + kbase);

  bool mz[4];
#pragma unroll
  for (int r = 0; r < 4; ++r) mz[r] = (mask[(mrow + r) * 16 + g16] == 0);

  const f32x4 zero = {0.f, 0.f, 0.f, 0.f};
  const int gw = blockIdx.x * 4 + w;

#define LD4(dst, src, off)                                                     \
  {                                                                            \
    dst[0] = *(const float4*)((src) + (off));                                  \
    dst[1] = *(const float4*)((src) + (off) + 4);                              \
    dst[2] = *(const float4*)((src) + (off) + 32);                             \
    dst[3] = *(const float4*)((src) + (off) + 36);                             \
  }

  float4 qs[4], ks[4], vs[4];
  const int off0 = gw * 2 * 1024 + g16 * 64 + kbase;
  LD4(qs, query, off0);
  LD4(ks, keys, off0);
  LD4(vs, values, off0);

#pragma unroll 1
  for (int i = 0; i < 2; ++i) {
    const int p = gw * 2 + i;

    // pack current position (waits on staged loads), then issue next-pos loads
    short8 aq0 = pack8(qs[0], qs[1]), aq1 = pack8(qs[2], qs[3]);
    short8 ak0 = pack8(ks[0], ks[1]), ak1 = pack8(ks[2], ks[3]);
    short8 av0 = pack8(vs[0], vs[1]), av1 = pack8(vs[2], vs[3]);
    if (i < 1) {
      const int off = off0 + 1024;
      LD4(qs, query, off);
      LD4(ks, keys, off);
      LD4(vs, values, off);
    }

    // t = xq @ M
    f32x4 tacc[4];
#pragma unroll
    for (int nc = 0; nc < 4; ++nc) {
      tacc[nc] = MFMA16(aq0, mtf[0][nc], zero);
      tacc[nc] = MFMA16(aq1, mtf[1][nc], tacc[nc]);
    }
#pragma unroll
    for (int nc = 0; nc < 4; ++nc)
#pragma unroll
      for (int r = 0; r < 4; ++r)
        t_lds[w][mrow + r][nc * 16 + g16] = f2bf(tacc[nc][r]);

    // stage raw v transposed: vT[d][g] (independent of t path; overlaps)
#pragma unroll
    for (int j = 0; j < 8; ++j) {
      vT_lds[w][kbase + j][g16] = av0[j];
      vT_lds[w][32 + kbase + j][g16] = av1[j];
    }

    // energy = t @ xk^T (B-operand = raw key fragments)
    short8 ea0 = *(const short8*)&t_lds[w][g16][kbase];
    short8 ea1 = *(const short8*)&t_lds[w][g16][32 + kbase];
    f32x4 acce = MFMA16(ea0, ak0, zero);
    acce = MFMA16(ea1, ak1, acce);

    // masked softmax across g (16 lanes); clamp replaces max-reduce
    const float SC = 0.045084220027780106f;  // (1/32) * log2(e)
    float av4[4];
#pragma unroll
    for (int r = 0; r < 4; ++r) {
      const float val = mz[r] ? -45.f : acce[r] * SC;
      const float pe = exp2f(val);
      float s = pe;
      s += __shfl_xor(s, 1, 16);
      s += __shfl_xor(s, 2, 16);
      s += __shfl_xor(s, 4, 16);
      s += __shfl_xor(s, 8, 16);
      av4[r] = pe * __builtin_amdgcn_rcpf(s);
    }

    float* ap = attn + (size_t)p * 256 + mrow * 16 + g16;
#pragma unroll
    for (int r = 0; r < 4; ++r) {
      ap[r * 16] = av4[r];
      p_lds[w][mrow + r][g16] = f2bf(av4[r]);
    }

    // o = P @ xv  (K=16 padded to 32 with zero A-frags)
    short8 pa;
    if (lane < 32) {
      pa = *(const short8*)&p_lds[w][g16][kbase];
    } else {
      short8 z = {0, 0, 0, 0, 0, 0, 0, 0};
      pa = z;
    }
    const int gsel = (lane < 32) ? kbase : 0;
#pragma unroll
    for (int nc = 0; nc < 4; ++nc) {
      short8 vb = *(const short8*)&vT_lds[w][nc * 16 + g16][gsel];
      f32x4 acco = MFMA16(pa, vb, zero);
#pragma unroll
      for (int r = 0; r < 4; ++r)
        t_lds[w][mrow + r][nc * 16 + g16] = f2bf(acco[r]);  // o into t region
    }

    // coalesced store: each lane 32B contiguous; wave = 2KB = full position
    const u16* orow = &t_lds[w][lane >> 2][(lane & 3) * 16];
    short8 s0 = *(const short8*)orow;
    short8 s1 = *(const short8*)(orow + 8);
    u16* dst = out2 + (size_t)p * 1024 + lane * 16;
    *(short8*)(void*)dst = s0;
    *(short8*)(void*)(dst + 8) = s1;
  }
#undef LD4
}

// ---------------- kernel 2: out = gather(out2) @ Wo2 + bo ----------------
// A is natural-layout out2; the transpose(0,2,1,3).reshape scramble is folded
// into the per-lane gather addresses of the A-tile staging.
__global__ __launch_bounds__(256, 2) void gemm_kernel(
    const u16* __restrict__ A, const u16* __restrict__ BT,
    const float* __restrict__ bo, float* __restrict__ C) {
  __shared__ __align__(16) u16 As[128 * 32];
  __shared__ __align__(16) u16 Bs[128 * 32];
  const int t = threadIdx.x, lane = t & 63;
  const int g16 = lane & 15, q4 = lane >> 4;
  const int w = t >> 6, wm = w >> 1, wn = w & 1;
  const int bm = blockIdx.x & 255, bn = blockIdx.x >> 8;

  f32x4 acc[4][4];
  const f32x4 zero = {0.f, 0.f, 0.f, 0.f};
#pragma unroll
  for (int mt = 0; mt < 4; ++mt)
#pragma unroll
    for (int nt = 0; nt < 4; ++nt) acc[mt][nt] = zero;

  const int am = t >> 2, ak = (t & 3) * 8;
  // scrambled row R -> natural out2 base: n=R>>12, h=(R&4095)>>8, lhi=R&255
  const int R0 = bm * 128 + am;
  const int R1 = R0 + 64;
  const size_t base0 =
      ((size_t)((R0 >> 12) * 4096 + (R0 & 255) * 16)) * 1024 +
      ((R0 & 4095) >> 8) * 64;
  const size_t base1 =
      ((size_t)((R1 >> 12) * 4096 + (R1 & 255) * 16)) * 1024 +
      ((R1 & 4095) >> 8) * 64;
  const u16* ga0 = A + base0 + ak;
  const u16* ga1 = A + base1 + ak;
  const u16* gb = BT + (size_t)(bn * 128 + am) * 1024 + ak;
  u16* lA = &As[t * 8];
  u16* lB = &Bs[t * 8];

  for (int kt = 0; kt < 32; ++kt) {
    __syncthreads();
    const int aoff = (kt >> 1) * 1024 + (kt & 1) * 32;  // col kt*32+ak gathered
    const int ko = kt * 32;
    GLD_LDS(ga0 + aoff, lA);
    GLD_LDS(ga1 + aoff, lA + 2048);
    GLD_LDS(gb + ko, lB);
    GLD_LDS(gb + 64 * 1024 + ko, lB + 2048);
    __syncthreads();

    short8 af[4], bf[4];
#pragma unroll
    for (int mt = 0; mt < 4; ++mt)
      af[mt] = *(const short8*)&As[(wm * 64 + mt * 16 + g16) * 32 + q4 * 8];
#pragma unroll
    for (int nt = 0; nt < 4; ++nt)
      bf[nt] = *(const short8*)&Bs[(wn * 64 + nt * 16 + g16) * 32 + q4 * 8];
#pragma unroll
    for (int mt = 0; mt < 4; ++mt)
#pragma unroll
      for (int nt = 0; nt < 4; ++nt)
        acc[mt][nt] = MFMA16(af[mt], bf[nt], acc[mt][nt]);
  }

#pragma unroll
  for (int nt = 0; nt < 4; ++nt) {
    const int col = bn * 128 + wn * 64 + nt * 16 + g16;
    const float bias = bo[col];
#pragma unroll
    for (int mt = 0; mt < 4; ++mt) {
#pragma unroll
      for (int r = 0; r < 4; ++r) {
        const int row = bm * 128 + wm * 64 + mt * 16 + q4 * 4 + r;
        C[(size_t)row * 1024 + col] = acc[mt][nt][r] + bias;
      }
    }
  }
}

extern "C" void kernel_launch(void* const* d_in, const int* in_sizes, int n_in,
                              void* d_out, int out_size, void* d_ws,
                              size_t ws_size, hipStream_t stream) {
  const float* values = (const float*)d_in[0];
  const float* keys   = (const float*)d_in[1];
  const float* query  = (const float*)d_in[2];
  const int*   mask   = (const int*)d_in[3];
  const float* Wv = (const float*)d_in[4];
  const float* Wk = (const float*)d_in[5];
  const float* Wq = (const float*)d_in[6];
  const float* Wo = (const float*)d_in[7];
  const float* bo = (const float*)d_in[8];

  float* out  = (float*)d_out;        // 8*4096*1024 fp32
  float* attn = out + 33554432;       // 8*4096*16*16 fp32

  u16* out2 = (u16*)d_ws;             // 32768 x 1024 bf16, natural layout
  u16* WoT2 = out2 + 33554432;        // 1024 x 1024 bf16
  u16* Mt   = WoT2 + 1048576;         // 64 x 64 bf16

  prep<<<257, 256, 0, stream>>>(Wv, Wk, Wq, Wo, WoT2, Mt);
  attn_kernel<<<4096, 256, 0, stream>>>(values, keys, query, mask, Mt, attn,
                                        out2);
  gemm_kernel<<<2048, 256, 0, stream>>>(out2, WoT2, bo, out);
}

// Round 6
// 231.829 us; speedup vs baseline: 1.8385x; 1.8385x over previous
//
#include <hip/hip_runtime.h>

typedef short short8 __attribute__((ext_vector_type(8)));
typedef float f32x4 __attribute__((ext_vector_type(4)));
typedef unsigned short u16;

#define MFMA16(a, b, c) __builtin_amdgcn_mfma_f32_16x16x32_bf16(a, b, c, 0, 0, 0)
#define GLD_LDS(g, l)                                                          \
  __builtin_amdgcn_global_load_lds(                                            \
      (__attribute__((address_space(1))) void*)(void*)(g),                     \
      (__attribute__((address_space(3))) void*)(l), 16, 0, 0)

__device__ __forceinline__ u16 f2bf(float f) {
  union { float f; unsigned u; } x; x.f = f;
  unsigned r = x.u + 0x7fffu + ((x.u >> 16) & 1u);
  return (u16)(r >> 16);
}

__device__ __forceinline__ short8 pack8(float4 a, float4 b) {
  short8 r;
  r[0] = (short)f2bf(a.x); r[1] = (short)f2bf(a.y);
  r[2] = (short)f2bf(a.z); r[3] = (short)f2bf(a.w);
  r[4] = (short)f2bf(b.x); r[5] = (short)f2bf(b.y);
  r[6] = (short)f2bf(b.z); r[7] = (short)f2bf(b.w);
  return r;
}

// ---------------- kernel 0: prep ----------------
// blocks 0..255: WoT2[n][h2*64+i] = bf16( sum_j Wv[i][j] * Wo[h2*64+j][n] )
// block 256:     Mt[n][k]         = bf16( sum_d Wk[n][d] * Wq[k][d] )
__global__ __launch_bounds__(256) void prep(const float* __restrict__ Wv,
                                            const float* __restrict__ Wk,
                                            const float* __restrict__ Wq,
                                            const float* __restrict__ Wo,
                                            u16* __restrict__ WoT2,
                                            u16* __restrict__ Mt) {
  __shared__ __align__(16) float A[64][65];
  __shared__ __align__(16) float B[64][68];
  const int t = threadIdx.x;
  const int r = t >> 2, c = (t & 3) * 16;
  if (blockIdx.x < 256) {
    const int tr = blockIdx.x >> 4, tc = blockIdx.x & 15;
#pragma unroll
    for (int u = 0; u < 4; ++u)
      *(float4*)&A[r][c + u * 4] = *(const float4*)(Wv + r * 64 + c + u * 4);
#pragma unroll
    for (int u = 0; u < 4; ++u)
      *(float4*)&B[r][c + u * 4] =
          *(const float4*)(Wo + (tr * 64 + r) * 1024 + tc * 64 + c + u * 4);
    __syncthreads();
    const int n = t & 63, i0 = (t >> 6) * 16;
    float acc[16];
#pragma unroll
    for (int ii = 0; ii < 16; ++ii) acc[ii] = 0.f;
    for (int j = 0; j < 64; ++j) {
      const float wo = B[j][n];
#pragma unroll
      for (int ii = 0; ii < 16; ++ii) acc[ii] += A[i0 + ii][j] * wo;
    }
    u16* dst = WoT2 + (size_t)(tc * 64 + n) * 1024 + tr * 64 + i0;
    short8 o0, o1;
#pragma unroll
    for (int jj = 0; jj < 8; ++jj) { o0[jj] = (short)f2bf(acc[jj]); o1[jj] = (short)f2bf(acc[8 + jj]); }
    *(short8*)(void*)dst = o0;
    *(short8*)(void*)(dst + 8) = o1;
  } else {
#pragma unroll
    for (int u = 0; u < 4; ++u)
      *(float4*)&A[r][c + u * 4] = *(const float4*)(Wq + r * 64 + c + u * 4);
#pragma unroll
    for (int u = 0; u < 4; ++u)
      *(float4*)&B[r][c + u * 4] = *(const float4*)(Wk + r * 64 + c + u * 4);
    __syncthreads();
    const int n = t & 63, k0 = (t >> 6) * 16;
    float acc[16];
#pragma unroll
    for (int ii = 0; ii < 16; ++ii) acc[ii] = 0.f;
    for (int d = 0; d < 64; ++d) {
      const float wk = B[n][d];
#pragma unroll
      for (int kk = 0; kk < 16; ++kk) acc[kk] += A[k0 + kk][d] * wk;
    }
    u16* dst = Mt + n * 64 + k0;
    short8 o0, o1;
#pragma unroll
    for (int jj = 0; jj < 8; ++jj) { o0[jj] = (short)f2bf(acc[jj]); o1[jj] = (short)f2bf(acc[8 + jj]); }
    *(short8*)(void*)dst = o0;
    *(short8*)(void*)(dst + 8) = o1;
  }
}

// ---------------- kernel 1: fused attention (per position) ----------------
// energy = (xq @ M) @ xk^T ; softmax ; o = P @ xv ; out2 natural [n][l][h][d]
// grid 4096 x 256, 2 positions/wave. launch_bounds min-waves stays at 3:
// it only CAPS the register allocator (6 -> VGPR=40 + massive spills, R4).
// Residency comes from actual usage: VGPR=80 -> 6 waves/SIMD, LDS 24.6KB ->
// 6 blocks/CU. Grid size was the real occupancy lever (R2: grid 1024 = 28%).
__global__ __launch_bounds__(256, 3) void attn_kernel(
    const float* __restrict__ values, const float* __restrict__ keys,
    const float* __restrict__ query, const int* __restrict__ mask,
    const u16* __restrict__ Mt, float* __restrict__ attn,
    u16* __restrict__ out2) {
  __shared__ __align__(16) u16 t_lds[4][16][72];   // t (16x64), then o
  __shared__ __align__(16) u16 vT_lds[4][64][24];  // [wave][d][g]
  __shared__ __align__(16) u16 p_lds[4][16][24];   // [wave][h][g]

  const int tid = threadIdx.x;
  const int w = tid >> 6, lane = tid & 63;
  const int g16 = lane & 15;
  const int q4 = lane >> 4;
  const int kbase = q4 * 8;
  const int mrow = q4 * 4;

  // M^T fragments (B-operand of t = xq @ M), resident.
  short8 mtf[2][4];
#pragma unroll
  for (int kb = 0; kb < 2; ++kb)
#pragma unroll
    for (int nc = 0; nc < 4; ++nc)
      mtf[kb][nc] =
          *(const short8*)(Mt + (nc * 16 + g16) * 64 + kb * 32 + kbase);

  bool mz[4];
#pragma unroll
  for (int r = 0; r < 4; ++r) mz[r] = (mask[(mrow + r) * 16 + g16] == 0);

  const f32x4 zero = {0.f, 0.f, 0.f, 0.f};
  const int gw = blockIdx.x * 4 + w;

#define LD4(dst, src, off)                                                     \
  {                                                                            \
    dst[0] = *(const float4*)((src) + (off));                                  \
    dst[1] = *(const float4*)((src) + (off) + 4);                              \
    dst[2] = *(const float4*)((src) + (off) + 32);                             \
    dst[3] = *(const float4*)((src) + (off) + 36);                             \
  }

  float4 qs[4], ks[4], vs[4];
  const int off0 = gw * 2 * 1024 + g16 * 64 + kbase;
  LD4(qs, query, off0);
  LD4(ks, keys, off0);
  LD4(vs, values, off0);

#pragma unroll 1
  for (int i = 0; i < 2; ++i) {
    const int p = gw * 2 + i;

    // pack current position (waits on staged loads), then issue next-pos loads
    short8 aq0 = pack8(qs[0], qs[1]), aq1 = pack8(qs[2], qs[3]);
    short8 ak0 = pack8(ks[0], ks[1]), ak1 = pack8(ks[2], ks[3]);
    short8 av0 = pack8(vs[0], vs[1]), av1 = pack8(vs[2], vs[3]);
    if (i < 1) {
      const int off = off0 + 1024;
      LD4(qs, query, off);
      LD4(ks, keys, off);
      LD4(vs, values, off);
    }

    // t = xq @ M
    f32x4 tacc[4];
#pragma unroll
    for (int nc = 0; nc < 4; ++nc) {
      tacc[nc] = MFMA16(aq0, mtf[0][nc], zero);
      tacc[nc] = MFMA16(aq1, mtf[1][nc], tacc[nc]);
    }
#pragma unroll
    for (int nc = 0; nc < 4; ++nc)
#pragma unroll
      for (int r = 0; r < 4; ++r)
        t_lds[w][mrow + r][nc * 16 + g16] = f2bf(tacc[nc][r]);

    // stage raw v transposed: vT[d][g] (independent of t path; overlaps)
#pragma unroll
    for (int j = 0; j < 8; ++j) {
      vT_lds[w][kbase + j][g16] = av0[j];
      vT_lds[w][32 + kbase + j][g16] = av1[j];
    }

    // energy = t @ xk^T (B-operand = raw key fragments)
    short8 ea0 = *(const short8*)&t_lds[w][g16][kbase];
    short8 ea1 = *(const short8*)&t_lds[w][g16][32 + kbase];
    f32x4 acce = MFMA16(ea0, ak0, zero);
    acce = MFMA16(ea1, ak1, acce);

    // masked softmax across g (16 lanes); clamp replaces max-reduce
    const float SC = 0.045084220027780106f;  // (1/32) * log2(e)
    float av4[4];
#pragma unroll
    for (int r = 0; r < 4; ++r) {
      const float val = mz[r] ? -45.f : acce[r] * SC;
      const float pe = exp2f(val);
      float s = pe;
      s += __shfl_xor(s, 1, 16);
      s += __shfl_xor(s, 2, 16);
      s += __shfl_xor(s, 4, 16);
      s += __shfl_xor(s, 8, 16);
      av4[r] = pe * __builtin_amdgcn_rcpf(s);
    }

    float* ap = attn + (size_t)p * 256 + mrow * 16 + g16;
#pragma unroll
    for (int r = 0; r < 4; ++r) {
      ap[r * 16] = av4[r];
      p_lds[w][mrow + r][g16] = f2bf(av4[r]);
    }

    // o = P @ xv  (K=16 padded to 32 with zero A-frags)
    short8 pa;
    if (lane < 32) {
      pa = *(const short8*)&p_lds[w][g16][kbase];
    } else {
      short8 z = {0, 0, 0, 0, 0, 0, 0, 0};
      pa = z;
    }
    const int gsel = (lane < 32) ? kbase : 0;
#pragma unroll
    for (int nc = 0; nc < 4; ++nc) {
      short8 vb = *(const short8*)&vT_lds[w][nc * 16 + g16][gsel];
      f32x4 acco = MFMA16(pa, vb, zero);
#pragma unroll
      for (int r = 0; r < 4; ++r)
        t_lds[w][mrow + r][nc * 16 + g16] = f2bf(acco[r]);  // o into t region
    }

    // coalesced store: each lane 32B contiguous; wave = 2KB = full position
    const u16* orow = &t_lds[w][lane >> 2][(lane & 3) * 16];
    short8 s0 = *(const short8*)orow;
    short8 s1 = *(const short8*)(orow + 8);
    u16* dst = out2 + (size_t)p * 1024 + lane * 16;
    *(short8*)(void*)dst = s0;
    *(short8*)(void*)(dst + 8) = s1;
  }
#undef LD4
}

// ---------------- kernel 2: out = gather(out2) @ Wo2 + bo ----------------
// A is natural-layout out2; the transpose(0,2,1,3).reshape scramble is folded
// into the per-lane gather addresses of the A-tile staging.
__global__ __launch_bounds__(256, 2) void gemm_kernel(
    const u16* __restrict__ A, const u16* __restrict__ BT,
    const float* __restrict__ bo, float* __restrict__ C) {
  __shared__ __align__(16) u16 As[128 * 32];
  __shared__ __align__(16) u16 Bs[128 * 32];
  const int t = threadIdx.x, lane = t & 63;
  const int g16 = lane & 15, q4 = lane >> 4;
  const int w = t >> 6, wm = w >> 1, wn = w & 1;
  const int bm = blockIdx.x & 255, bn = blockIdx.x >> 8;

  f32x4 acc[4][4];
  const f32x4 zero = {0.f, 0.f, 0.f, 0.f};
#pragma unroll
  for (int mt = 0; mt < 4; ++mt)
#pragma unroll
    for (int nt = 0; nt < 4; ++nt) acc[mt][nt] = zero;

  const int am = t >> 2, ak = (t & 3) * 8;
  // scrambled row R -> natural out2 base: n=R>>12, h=(R&4095)>>8, lhi=R&255
  const int R0 = bm * 128 + am;
  const int R1 = R0 + 64;
  const size_t base0 =
      ((size_t)((R0 >> 12) * 4096 + (R0 & 255) * 16)) * 1024 +
      ((R0 & 4095) >> 8) * 64;
  const size_t base1 =
      ((size_t)((R1 >> 12) * 4096 + (R1 & 255) * 16)) * 1024 +
      ((R1 & 4095) >> 8) * 64;
  const u16* ga0 = A + base0 + ak;
  const u16* ga1 = A + base1 + ak;
  const u16* gb = BT + (size_t)(bn * 128 + am) * 1024 + ak;
  u16* lA = &As[t * 8];
  u16* lB = &Bs[t * 8];

  for (int kt = 0; kt < 32; ++kt) {
    __syncthreads();
    const int aoff = (kt >> 1) * 1024 + (kt & 1) * 32;  // col kt*32+ak gathered
    const int ko = kt * 32;
    GLD_LDS(ga0 + aoff, lA);
    GLD_LDS(ga1 + aoff, lA + 2048);
    GLD_LDS(gb + ko, lB);
    GLD_LDS(gb + 64 * 1024 + ko, lB + 2048);
    __syncthreads();

    short8 af[4], bf[4];
#pragma unroll
    for (int mt = 0; mt < 4; ++mt)
      af[mt] = *(const short8*)&As[(wm * 64 + mt * 16 + g16) * 32 + q4 * 8];
#pragma unroll
    for (int nt = 0; nt < 4; ++nt)
      bf[nt] = *(const short8*)&Bs[(wn * 64 + nt * 16 + g16) * 32 + q4 * 8];
#pragma unroll
    for (int mt = 0; mt < 4; ++mt)
#pragma unroll
      for (int nt = 0; nt < 4; ++nt)
        acc[mt][nt] = MFMA16(af[mt], bf[nt], acc[mt][nt]);
  }

#pragma unroll
  for (int nt = 0; nt < 4; ++nt) {
    const int col = bn * 128 + wn * 64 + nt * 16 + g16;
    const float bias = bo[col];
#pragma unroll
    for (int mt = 0; mt < 4; ++mt) {
#pragma unroll
      for (int r = 0; r < 4; ++r) {
        const int row = bm * 128 + wm * 64 + mt * 16 + q4 * 4 + r;
        C[(size_t)row * 1024 + col] = acc[mt][nt][r] + bias;
      }
    }
  }
}

extern "C" void kernel_launch(void* const* d_in, const int* in_sizes, int n_in,
                              void* d_out, int out_size, void* d_ws,
                              size_t ws_size, hipStream_t stream) {
  const float* values = (const float*)d_in[0];
  const float* keys   = (const float*)d_in[1];
  const float* query  = (const float*)d_in[2];
  const int*   mask   = (const int*)d_in[3];
  const float* Wv = (const float*)d_in[4];
  const float* Wk = (const float*)d_in[5];
  const float* Wq = (const float*)d_in[6];
  const float* Wo = (const float*)d_in[7];
  const float* bo = (const float*)d_in[8];

  float* out  = (float*)d_out;        // 8*4096*1024 fp32
  float* attn = out + 33554432;       // 8*4096*16*16 fp32

  u16* out2 = (u16*)d_ws;             // 32768 x 1024 bf16, natural layout
  u16* WoT2 = out2 + 33554432;        // 1024 x 1024 bf16
  u16* Mt   = WoT2 + 1048576;         // 64 x 64 bf16

  prep<<<257, 256, 0, stream>>>(Wv, Wk, Wq, Wo, WoT2, Mt);
  attn_kernel<<<4096, 256, 0, stream>>>(values, keys, query, mask, Mt, attn,
                                        out2);
  gemm_kernel<<<2048, 256, 0, stream>>>(out2, WoT2, bo, out);
}

// Round 7
// 229.053 us; speedup vs baseline: 1.8608x; 1.0121x over previous
//
#include <hip/hip_runtime.h>

typedef short short8 __attribute__((ext_vector_type(8)));
typedef float f32x4 __attribute__((ext_vector_type(4)));
typedef unsigned short u16;

#define MFMA16(a, b, c) __builtin_amdgcn_mfma_f32_16x16x32_bf16(a, b, c, 0, 0, 0)
#define GLD_LDS(g, l)                                                          \
  __builtin_amdgcn_global_load_lds(                                            \
      (__attribute__((address_space(1))) void*)(void*)(g),                     \
      (__attribute__((address_space(3))) void*)(l), 16, 0, 0)

__device__ __forceinline__ u16 f2bf(float f) {
  union { float f; unsigned u; } x; x.f = f;
  unsigned r = x.u + 0x7fffu + ((x.u >> 16) & 1u);
  return (u16)(r >> 16);
}

__device__ __forceinline__ short8 pack8(float4 a, float4 b) {
  short8 r;
  r[0] = (short)f2bf(a.x); r[1] = (short)f2bf(a.y);
  r[2] = (short)f2bf(a.z); r[3] = (short)f2bf(a.w);
  r[4] = (short)f2bf(b.x); r[5] = (short)f2bf(b.y);
  r[6] = (short)f2bf(b.z); r[7] = (short)f2bf(b.w);
  return r;
}

// ---------------- kernel 0: prep ----------------
// blocks 0..255: WoT2[n][h2*64+i] = bf16( sum_j Wv[i][j] * Wo[h2*64+j][n] )
// block 256:     Mt[n][k]         = bf16( sum_d Wk[n][d] * Wq[k][d] )
__global__ __launch_bounds__(256) void prep(const float* __restrict__ Wv,
                                            const float* __restrict__ Wk,
                                            const float* __restrict__ Wq,
                                            const float* __restrict__ Wo,
                                            u16* __restrict__ WoT2,
                                            u16* __restrict__ Mt) {
  __shared__ __align__(16) float A[64][65];
  __shared__ __align__(16) float B[64][68];
  const int t = threadIdx.x;
  const int r = t >> 2, c = (t & 3) * 16;
  if (blockIdx.x < 256) {
    const int tr = blockIdx.x >> 4, tc = blockIdx.x & 15;
#pragma unroll
    for (int u = 0; u < 4; ++u)
      *(float4*)&A[r][c + u * 4] = *(const float4*)(Wv + r * 64 + c + u * 4);
#pragma unroll
    for (int u = 0; u < 4; ++u)
      *(float4*)&B[r][c + u * 4] =
          *(const float4*)(Wo + (tr * 64 + r) * 1024 + tc * 64 + c + u * 4);
    __syncthreads();
    const int n = t & 63, i0 = (t >> 6) * 16;
    float acc[16];
#pragma unroll
    for (int ii = 0; ii < 16; ++ii) acc[ii] = 0.f;
    for (int j = 0; j < 64; ++j) {
      const float wo = B[j][n];
#pragma unroll
      for (int ii = 0; ii < 16; ++ii) acc[ii] += A[i0 + ii][j] * wo;
    }
    u16* dst = WoT2 + (size_t)(tc * 64 + n) * 1024 + tr * 64 + i0;
    short8 o0, o1;
#pragma unroll
    for (int jj = 0; jj < 8; ++jj) { o0[jj] = (short)f2bf(acc[jj]); o1[jj] = (short)f2bf(acc[8 + jj]); }
    *(short8*)(void*)dst = o0;
    *(short8*)(void*)(dst + 8) = o1;
  } else {
#pragma unroll
    for (int u = 0; u < 4; ++u)
      *(float4*)&A[r][c + u * 4] = *(const float4*)(Wq + r * 64 + c + u * 4);
#pragma unroll
    for (int u = 0; u < 4; ++u)
      *(float4*)&B[r][c + u * 4] = *(const float4*)(Wk + r * 64 + c + u * 4);
    __syncthreads();
    const int n = t & 63, k0 = (t >> 6) * 16;
    float acc[16];
#pragma unroll
    for (int ii = 0; ii < 16; ++ii) acc[ii] = 0.f;
    for (int d = 0; d < 64; ++d) {
      const float wk = B[n][d];
#pragma unroll
      for (int kk = 0; kk < 16; ++kk) acc[kk] += A[k0 + kk][d] * wk;
    }
    u16* dst = Mt + n * 64 + k0;
    short8 o0, o1;
#pragma unroll
    for (int jj = 0; jj < 8; ++jj) { o0[jj] = (short)f2bf(acc[jj]); o1[jj] = (short)f2bf(acc[8 + jj]); }
    *(short8*)(void*)dst = o0;
    *(short8*)(void*)(dst + 8) = o1;
  }
}

// ---------------- kernel 1: fused attention, 1 position per wave ----------
// VGPR-diet version: no next-pos staging, Mt fragments re-read from L2 per
// phase (2 live at a time), forced into the <=64-VGPR bucket for 8 waves/SIMD.
__global__ __launch_bounds__(256, 8) void attn_kernel(
    const float* __restrict__ values, const float* __restrict__ keys,
    const float* __restrict__ query, const int* __restrict__ mask,
    const u16* __restrict__ Mt, float* __restrict__ attn,
    u16* __restrict__ out2) {
  __shared__ __align__(16) u16 t_lds[4][16][72];   // t (16x64), then o
  __shared__ __align__(16) u16 vT_lds[4][64][24];  // [wave][d][g]
  __shared__ __align__(16) u16 p_lds[4][16][24];   // [wave][h][g]

  const int tid = threadIdx.x;
  const int w = tid >> 6, lane = tid & 63;
  const int g16 = lane & 15;
  const int q4 = lane >> 4;
  const int kbase = q4 * 8;
  const int mrow = q4 * 4;

  const int p = blockIdx.x * 4 + w;  // one position per wave
  const int off = p * 1024 + g16 * 64 + kbase;

  // mask bits packed into one VGPR
  int mzb = 0;
#pragma unroll
  for (int r = 0; r < 4; ++r)
    mzb |= (mask[(mrow + r) * 16 + g16] == 0) ? (1 << r) : 0;

  const f32x4 zero = {0.f, 0.f, 0.f, 0.f};

  // ---- load q,k then v; pack; stage vT early so staging regs die ----
  float4 qa0 = *(const float4*)(query + off);
  float4 qa1 = *(const float4*)(query + off + 4);
  float4 qb0 = *(const float4*)(query + off + 32);
  float4 qb1 = *(const float4*)(query + off + 36);
  float4 ka0 = *(const float4*)(keys + off);
  float4 ka1 = *(const float4*)(keys + off + 4);
  float4 kb0 = *(const float4*)(keys + off + 32);
  float4 kb1 = *(const float4*)(keys + off + 36);
  float4 va0 = *(const float4*)(values + off);
  float4 va1 = *(const float4*)(values + off + 4);
  float4 vb0 = *(const float4*)(values + off + 32);
  float4 vb1 = *(const float4*)(values + off + 36);

  short8 aq0 = pack8(qa0, qa1), aq1 = pack8(qb0, qb1);
  short8 ak0 = pack8(ka0, ka1), ak1 = pack8(kb0, kb1);
  {
    short8 av0 = pack8(va0, va1), av1 = pack8(vb0, vb1);
#pragma unroll
    for (int j = 0; j < 8; ++j) {
      vT_lds[w][kbase + j][g16] = av0[j];
      vT_lds[w][32 + kbase + j][g16] = av1[j];
    }
  }

  // ---- t = xq @ M, phased: nc={0,1} then {2,3}; Mt frags from L2 ----
  const u16* mtp = Mt + g16 * 64 + kbase;  // + nc*1024 + kb*32
  {
    short8 m00 = *(const short8*)(mtp + 0 * 1024);
    short8 m01 = *(const short8*)(mtp + 0 * 1024 + 32);
    short8 m10 = *(const short8*)(mtp + 1 * 1024);
    short8 m11 = *(const short8*)(mtp + 1 * 1024 + 32);
    f32x4 t0 = MFMA16(aq0, m00, zero);
    t0 = MFMA16(aq1, m01, t0);
    f32x4 t1 = MFMA16(aq0, m10, zero);
    t1 = MFMA16(aq1, m11, t1);
#pragma unroll
    for (int r = 0; r < 4; ++r) {
      t_lds[w][mrow + r][g16] = f2bf(t0[r]);
      t_lds[w][mrow + r][16 + g16] = f2bf(t1[r]);
    }
  }
  {
    short8 m20 = *(const short8*)(mtp + 2 * 1024);
    short8 m21 = *(const short8*)(mtp + 2 * 1024 + 32);
    short8 m30 = *(const short8*)(mtp + 3 * 1024);
    short8 m31 = *(const short8*)(mtp + 3 * 1024 + 32);
    f32x4 t2 = MFMA16(aq0, m20, zero);
    t2 = MFMA16(aq1, m21, t2);
    f32x4 t3 = MFMA16(aq0, m30, zero);
    t3 = MFMA16(aq1, m31, t3);
#pragma unroll
    for (int r = 0; r < 4; ++r) {
      t_lds[w][mrow + r][32 + g16] = f2bf(t2[r]);
      t_lds[w][mrow + r][48 + g16] = f2bf(t3[r]);
    }
  }

  // ---- energy = t @ xk^T ----
  short8 ea0 = *(const short8*)&t_lds[w][g16][kbase];
  short8 ea1 = *(const short8*)&t_lds[w][g16][32 + kbase];
  f32x4 acce = MFMA16(ea0, ak0, zero);
  acce = MFMA16(ea1, ak1, acce);

  // ---- masked softmax across g (16 lanes) ----
  const float SC = 0.045084220027780106f;  // (1/32) * log2(e)
  float* ap = attn + (size_t)p * 256 + mrow * 16 + g16;
#pragma unroll
  for (int r = 0; r < 4; ++r) {
    const float val = ((mzb >> r) & 1) ? -45.f : acce[r] * SC;
    const float pe = exp2f(val);
    float s = pe;
    s += __shfl_xor(s, 1, 16);
    s += __shfl_xor(s, 2, 16);
    s += __shfl_xor(s, 4, 16);
    s += __shfl_xor(s, 8, 16);
    const float a = pe * __builtin_amdgcn_rcpf(s);
    ap[r * 16] = a;
    p_lds[w][mrow + r][g16] = f2bf(a);
  }

  // ---- o = P @ xv (K=16 padded to 32 with zero A-frags) ----
  short8 pa;
  if (lane < 32) {
    pa = *(const short8*)&p_lds[w][g16][kbase];
  } else {
    short8 z = {0, 0, 0, 0, 0, 0, 0, 0};
    pa = z;
  }
  const int gsel = (lane < 32) ? kbase : 0;
#pragma unroll
  for (int nc = 0; nc < 4; ++nc) {
    short8 vb = *(const short8*)&vT_lds[w][nc * 16 + g16][gsel];
    f32x4 acco = MFMA16(pa, vb, zero);
#pragma unroll
    for (int r = 0; r < 4; ++r)
      t_lds[w][mrow + r][nc * 16 + g16] = f2bf(acco[r]);  // o into t region
  }

  // ---- coalesced out2 store: wave writes its position's 2KB ----
  const u16* orow = &t_lds[w][lane >> 2][(lane & 3) * 16];
  short8 s0 = *(const short8*)orow;
  short8 s1 = *(const short8*)(orow + 8);
  u16* dst = out2 + (size_t)p * 1024 + lane * 16;
  *(short8*)(void*)dst = s0;
  *(short8*)(void*)(dst + 8) = s1;
}

// ---------------- kernel 2: out = gather(out2) @ Wo2 + bo ----------------
// A is natural-layout out2; the transpose(0,2,1,3).reshape scramble is folded
// into the per-lane gather addresses of the A-tile staging.
__global__ __launch_bounds__(256, 2) void gemm_kernel(
    const u16* __restrict__ A, const u16* __restrict__ BT,
    const float* __restrict__ bo, float* __restrict__ C) {
  __shared__ __align__(16) u16 As[128 * 32];
  __shared__ __align__(16) u16 Bs[128 * 32];
  const int t = threadIdx.x, lane = t & 63;
  const int g16 = lane & 15, q4 = lane >> 4;
  const int w = t >> 6, wm = w >> 1, wn = w & 1;
  const int bm = blockIdx.x & 255, bn = blockIdx.x >> 8;

  f32x4 acc[4][4];
  const f32x4 zero = {0.f, 0.f, 0.f, 0.f};
#pragma unroll
  for (int mt = 0; mt < 4; ++mt)
#pragma unroll
    for (int nt = 0; nt < 4; ++nt) acc[mt][nt] = zero;

  const int am = t >> 2, ak = (t & 3) * 8;
  // scrambled row R -> natural out2 base: n=R>>12, h=(R&4095)>>8, lhi=R&255
  const int R0 = bm * 128 + am;
  const int R1 = R0 + 64;
  const size_t base0 =
      ((size_t)((R0 >> 12) * 4096 + (R0 & 255) * 16)) * 1024 +
      ((R0 & 4095) >> 8) * 64;
  const size_t base1 =
      ((size_t)((R1 >> 12) * 4096 + (R1 & 255) * 16)) * 1024 +
      ((R1 & 4095) >> 8) * 64;
  const u16* ga0 = A + base0 + ak;
  const u16* ga1 = A + base1 + ak;
  const u16* gb = BT + (size_t)(bn * 128 + am) * 1024 + ak;
  u16* lA = &As[t * 8];
  u16* lB = &Bs[t * 8];

  for (int kt = 0; kt < 32; ++kt) {
    __syncthreads();
    const int aoff = (kt >> 1) * 1024 + (kt & 1) * 32;  // col kt*32+ak gathered
    const int ko = kt * 32;
    GLD_LDS(ga0 + aoff, lA);
    GLD_LDS(ga1 + aoff, lA + 2048);
    GLD_LDS(gb + ko, lB);
    GLD_LDS(gb + 64 * 1024 + ko, lB + 2048);
    __syncthreads();

    short8 af[4], bf[4];
#pragma unroll
    for (int mt = 0; mt < 4; ++mt)
      af[mt] = *(const short8*)&As[(wm * 64 + mt * 16 + g16) * 32 + q4 * 8];
#pragma unroll
    for (int nt = 0; nt < 4; ++nt)
      bf[nt] = *(const short8*)&Bs[(wn * 64 + nt * 16 + g16) * 32 + q4 * 8];
#pragma unroll
    for (int mt = 0; mt < 4; ++mt)
#pragma unroll
      for (int nt = 0; nt < 4; ++nt)
        acc[mt][nt] = MFMA16(af[mt], bf[nt], acc[mt][nt]);
  }

#pragma unroll
  for (int nt = 0; nt < 4; ++nt) {
    const int col = bn * 128 + wn * 64 + nt * 16 + g16;
    const float bias = bo[col];
#pragma unroll
    for (int mt = 0; mt < 4; ++mt) {
#pragma unroll
      for (int r = 0; r < 4; ++r) {
        const int row = bm * 128 + wm * 64 + mt * 16 + q4 * 4 + r;
        C[(size_t)row * 1024 + col] = acc[mt][nt][r] + bias;
      }
    }
  }
}

extern "C" void kernel_launch(void* const* d_in, const int* in_sizes, int n_in,
                              void* d_out, int out_size, void* d_ws,
                              size_t ws_size, hipStream_t stream) {
  const float* values = (const float*)d_in[0];
  const float* keys   = (const float*)d_in[1];
  const float* query  = (const float*)d_in[2];
  const int*   mask   = (const int*)d_in[3];
  const float* Wv = (const float*)d_in[4];
  const float* Wk = (const float*)d_in[5];
  const float* Wq = (const float*)d_in[6];
  const float* Wo = (const float*)d_in[7];
  const float* bo = (const float*)d_in[8];

  float* out  = (float*)d_out;        // 8*4096*1024 fp32
  float* attn = out + 33554432;       // 8*4096*16*16 fp32

  u16* out2 = (u16*)d_ws;             // 32768 x 1024 bf16, natural layout
  u16* WoT2 = out2 + 33554432;        // 1024 x 1024 bf16
  u16* Mt   = WoT2 + 1048576;         // 64 x 64 bf16

  prep<<<257, 256, 0, stream>>>(Wv, Wk, Wq, Wo, WoT2, Mt);
  attn_kernel<<<8192, 256, 0, stream>>>(values, keys, query, mask, Mt, attn,
                                        out2);
  gemm_kernel<<<2048, 256, 0, stream>>>(out2, WoT2, bo, out);
}